// Round 8
// baseline (421.160 us; speedup 1.0000x reference)
//
#include <hip/hip_runtime.h>
#include <hip/hip_fp16.h>
#include <stdint.h>

#define N_NODES   100000
#define N_TAB     (N_NODES + 1)   // +1 sentinel zero-row for CSR padding
#define N_EDGES   3200000
#define F_IN      128
#define F_HID     64
#define F_OUT     16

typedef _Float16 h2v __attribute__((ext_vector_type(2)));
typedef int   i4v __attribute__((ext_vector_type(4)));
typedef float f2v __attribute__((ext_vector_type(2)));

// bucket partition params
#define BSHIFT    8
#define NBUCK     391                  // ceil(100000 / 256)
#define NBLK_P    512                  // partition blocks
#define CHUNK_E   (N_EDGES / NBLK_P)   // 6250 edges per block

// gemm1 tiling
#define G1_TM     128
#define G1_BLOCKS ((N_TAB + G1_TM - 1) / G1_TM)   // 782
#define XS_LD     132

#define CSR_CAP   3500000              // E + 3*N worst-case padding

// ---- workspace layout (bytes), 16B-aligned ----
#define OFF_CNT      0                 // int[N]
#define OFF_ROWSTART 400000            // int[N+1] (padded rowstarts, mult of 4)
#define OFF_DINV     800016            // float[N+1]
#define OFF_BSUM     1200032           // int[128]
#define OFF_FLAG     1200544           // int
#define OFF_BSTART   1200560           // int[NBUCK+1]
#define OFF_BTOT     1202128           // int[NBUCK+pad]
#define OFF_BHIST    1203728           // int[NBUCK*NBLK_P]
#define OFF_CSR      2004496           // int[CSR_CAP]
#define OFF_HS1      16004496          // half[4][N_TAB][16]  (chunk-major)
#define OFF_OUT1     28804624          // float[N*64]
#define OFF_HS2      54404624          // half[N_TAB*16]
#define OFF_PAIRS    OFF_OUT1          // uint[E] — aliases out1 (dead by then)

// ---------------- edge dtype detection + loaders ----------------
__global__ void k_detect(const void* __restrict__ ei, int* __restrict__ flag) {
    const unsigned* u = (const unsigned*)ei;
    int ok = 1;
    for (int i = 0; i < 64; ++i) {
        unsigned lo = u[2 * i], hi = u[2 * i + 1];
        if (hi != 0u || lo >= 100000u) { ok = 0; break; }
    }
    *flag = ok;   // 1 => int64 edge data
}

__device__ __forceinline__ int edge_src(const void* ei, int is64, int e) {
    return is64 ? (int)((const long long*)ei)[e] : ((const int*)ei)[e];
}
__device__ __forceinline__ int edge_dst(const void* ei, int is64, int e) {
    return is64 ? (int)((const long long*)ei)[N_EDGES + e]
                : ((const int*)ei)[N_EDGES + e];
}

// ---------------- pass 1: per-block bucket histogram ----------------
__global__ __launch_bounds__(256) void k_bhist(const void* __restrict__ ei,
                                               const int* __restrict__ flag,
                                               int* __restrict__ bhist) {
    __shared__ int h[NBUCK];
    for (int i = threadIdx.x; i < NBUCK; i += 256) h[i] = 0;
    __syncthreads();
    int is64 = *flag;
    int base = blockIdx.x * CHUNK_E;
    for (int i = threadIdx.x; i < CHUNK_E; i += 256)
        atomicAdd(&h[edge_dst(ei, is64, base + i) >> BSHIFT], 1);
    __syncthreads();
    for (int i = threadIdx.x; i < NBUCK; i += 256)
        bhist[i * NBLK_P + blockIdx.x] = h[i];
}

// ---------------- pass 2a: per-bucket totals ----------------
__global__ __launch_bounds__(128) void k_btotal(const int* __restrict__ bhist,
                                                int* __restrict__ btot) {
    __shared__ int sd[128];
    int b = blockIdx.x, t = threadIdx.x;
    const int* p = bhist + b * NBLK_P;
    int s = p[t] + p[t + 128] + p[t + 256] + p[t + 384];
    sd[t] = s;
    __syncthreads();
    for (int off = 64; off > 0; off >>= 1) {
        if (t < off) sd[t] += sd[t + off];
        __syncthreads();
    }
    if (t == 0) btot[b] = sd[0];
}

// ---------------- pass 2b: scan bucket totals -> bucket starts ----------------
__global__ __launch_bounds__(512) void k_bscan(const int* __restrict__ btot,
                                               int* __restrict__ bstart) {
    __shared__ int sd[512];
    int t = threadIdx.x;
    int v = (t < NBUCK) ? btot[t] : 0;
    sd[t] = v;
    __syncthreads();
    for (int off = 1; off < 512; off <<= 1) {
        int a = (t >= off) ? sd[t - off] : 0;
        __syncthreads();
        sd[t] += a;
        __syncthreads();
    }
    if (t < NBUCK) bstart[t] = sd[t] - v;
    if (t == 0) bstart[NBUCK] = N_EDGES;
}

// ---------------- pass 2c: per-bucket scan of per-block counts ----------------
__global__ __launch_bounds__(512) void k_boffs(int* __restrict__ bhist,
                                               const int* __restrict__ bstart) {
    __shared__ int sd[512];
    int b = blockIdx.x, t = threadIdx.x;
    int v = bhist[b * NBLK_P + t];
    sd[t] = v;
    __syncthreads();
    for (int off = 1; off < 512; off <<= 1) {
        int a = (t >= off) ? sd[t - off] : 0;
        __syncthreads();
        sd[t] += a;
        __syncthreads();
    }
    bhist[b * NBLK_P + t] = bstart[b] + sd[t] - v;
}

// ---------------- pass 3: partition into bucket-grouped packed pairs ----------------
__global__ __launch_bounds__(256) void k_partition(const void* __restrict__ ei,
                                                   const int* __restrict__ flag,
                                                   const int* __restrict__ bhist,
                                                   unsigned* __restrict__ pairs) {
    __shared__ int cur[NBUCK];
    for (int i = threadIdx.x; i < NBUCK; i += 256)
        cur[i] = bhist[i * NBLK_P + blockIdx.x];
    __syncthreads();
    int is64 = *flag;
    int base = blockIdx.x * CHUNK_E;
    for (int i = threadIdx.x; i < CHUNK_E; i += 256) {
        int e = base + i;
        int s = edge_src(ei, is64, e);
        int d = edge_dst(ei, is64, e);
        int p = atomicAdd(&cur[d >> BSHIFT], 1);
        pairs[p] = ((unsigned)s << 8) | (unsigned)(d & 255);
    }
}

// ---------------- pass 4: per-bucket dst counts + dinv ----------------
__global__ __launch_bounds__(256) void k_dcount(const unsigned* __restrict__ pairs,
                                                const int* __restrict__ bstart,
                                                int* __restrict__ cnt,
                                                float* __restrict__ dinv) {
    __shared__ int c[256];
    int b = blockIdx.x, t = threadIdx.x;
    c[t] = 0;
    __syncthreads();
    int s0 = bstart[b], s1 = bstart[b + 1];
    for (int i = s0 + t; i < s1; i += 256)
        atomicAdd(&c[pairs[i] & 255u], 1);
    __syncthreads();
    int d = (b << BSHIFT) + t;
    if (d < N_NODES) {
        cnt[d] = c[t];
        dinv[d] = rsqrtf((float)c[t] + 1.0f);
    } else if (d == N_NODES) {
        dinv[d] = 0.f;   // sentinel
    }
}

// ---------------- exclusive scan of PADDED cnt -> rowstart ----------------
__global__ __launch_bounds__(256) void k_scan_partial(const int* __restrict__ cnt,
                                                      int* __restrict__ bsum) {
    __shared__ int sd[256];
    int t = threadIdx.x;
    int base = blockIdx.x * 1024 + t * 4;
    int s = 0;
#pragma unroll
    for (int c = 0; c < 4; ++c)
        if (base + c < N_NODES) s += (cnt[base + c] + 3) & ~3;
    sd[t] = s;
    __syncthreads();
    for (int off = 128; off > 0; off >>= 1) {
        if (t < off) sd[t] += sd[t + off];
        __syncthreads();
    }
    if (t == 0) bsum[blockIdx.x] = sd[0];
}

__global__ void k_scan_bsums(int* __restrict__ bsum) {  // <<<1,128>>>, NB=98
    __shared__ int sd[128];
    int t = threadIdx.x;
    sd[t] = (t < 98) ? bsum[t] : 0;
    __syncthreads();
    for (int off = 1; off < 128; off <<= 1) {
        int add = (t >= off) ? sd[t - off] : 0;
        __syncthreads();
        sd[t] += add;
        __syncthreads();
    }
    if (t < 98) bsum[t] = (t == 0) ? 0 : sd[t - 1];
}

__global__ __launch_bounds__(256) void k_scan_final(const int* __restrict__ cnt,
                                                    const int* __restrict__ bsum,
                                                    int* __restrict__ rowstart) {
    __shared__ int sd[256];
    int t = threadIdx.x;
    int base = blockIdx.x * 1024 + t * 4;
    int v[4];
#pragma unroll
    for (int c = 0; c < 4; ++c)
        v[c] = (base + c < N_NODES) ? ((cnt[base + c] + 3) & ~3) : 0;
    int tsum = v[0] + v[1] + v[2] + v[3];
    sd[t] = tsum;
    __syncthreads();
    for (int off = 1; off < 256; off <<= 1) {
        int add = (t >= off) ? sd[t - off] : 0;
        __syncthreads();
        sd[t] += add;
        __syncthreads();
    }
    int run = bsum[blockIdx.x] + sd[t] - tsum;
#pragma unroll
    for (int c = 0; c < 4; ++c) {
        if (base + c < N_NODES) rowstart[base + c] = run;
        run += v[c];
        if (base + c == N_NODES - 1) rowstart[N_NODES] = run;
    }
}

// ---------------- pass 5: sentinel-fill + CSR placement ----------------
__global__ __launch_bounds__(256) void k_place(const unsigned* __restrict__ pairs,
                                               const int* __restrict__ bstart,
                                               const int* __restrict__ rowstart,
                                               int* __restrict__ csr) {
    __shared__ int pos[256];
    int b = blockIdx.x, t = threadIdx.x;
    int dbase = b << BSHIFT;
    int d = dbase + t;
    pos[t] = (d < N_NODES) ? rowstart[d] : 0;
    int hiIdx = dbase + 256; if (hiIdx > N_NODES) hiIdx = N_NODES;
    int lo = rowstart[dbase], hi = rowstart[hiIdx];
    for (int i = lo + t; i < hi; i += 256) csr[i] = N_NODES;  // sentinel pad
    __syncthreads();
    int s0 = bstart[b], s1 = bstart[b + 1];
    for (int i = s0 + t; i < s1; i += 256) {
        unsigned pr = pairs[i];
        int p = atomicAdd(&pos[pr & 255u], 1);
        csr[p] = (int)(pr >> 8);
    }
}

// ---------------- GEMM1 (LDS-tiled): hs1[chunk][node][16] = (x@W1)*dinv ----
__global__ __launch_bounds__(256) void k_gemm1(const float* __restrict__ x,
                                               const float* __restrict__ W1,
                                               const float* __restrict__ dinv,
                                               __half* __restrict__ hs1) {
    __shared__ float xsT[64 * XS_LD];
    __shared__ float ws[64 * 64];
    int t = threadIdx.x;
    int nblock = blockIdx.x * G1_TM;
    int ng = t >> 4, og = t & 15;
    int n0 = ng * 8;
    float acc[8][4] = {};

    int snode = nblock + (t >> 1);
    int koff = (t & 1) * 32;
    int nl = t >> 1;

    for (int chunk = 0; chunk < 2; ++chunk) {
        int kbase = chunk * 64;
        {
            float4 v[8];
            if (snode < N_NODES) {
                const float4* src = (const float4*)(x + (size_t)snode * F_IN + kbase + koff);
#pragma unroll
                for (int c = 0; c < 8; ++c) v[c] = src[c];
            } else {
#pragma unroll
                for (int c = 0; c < 8; ++c) v[c] = make_float4(0.f, 0.f, 0.f, 0.f);
            }
#pragma unroll
            for (int c = 0; c < 8; ++c) {
                int k = koff + c * 4;
                xsT[(k + 0) * XS_LD + nl] = v[c].x;
                xsT[(k + 1) * XS_LD + nl] = v[c].y;
                xsT[(k + 2) * XS_LD + nl] = v[c].z;
                xsT[(k + 3) * XS_LD + nl] = v[c].w;
            }
        }
        {
            const float4* wsrc = (const float4*)(W1 + kbase * F_HID);
            float4* wdst = (float4*)ws;
#pragma unroll
            for (int c = 0; c < 4; ++c) wdst[c * 256 + t] = wsrc[c * 256 + t];
        }
        __syncthreads();

#pragma unroll 4
        for (int k = 0; k < 64; ++k) {
            const float4* xr = (const float4*)(xsT + k * XS_LD + n0);
            float4 a0 = xr[0], a1 = xr[1];
            float4 bv = *(const float4*)(ws + k * 64 + og * 4);
            float a[8] = {a0.x, a0.y, a0.z, a0.w, a1.x, a1.y, a1.z, a1.w};
            float bb[4] = {bv.x, bv.y, bv.z, bv.w};
#pragma unroll
            for (int i = 0; i < 8; ++i)
#pragma unroll
                for (int j = 0; j < 4; ++j)
                    acc[i][j] += a[i] * bb[j];
        }
        __syncthreads();
    }

    // epilogue: chunk-major layout hs1[(og>>2)*N_TAB + node][16] + (og&3)*4
#pragma unroll
    for (int i = 0; i < 8; ++i) {
        int node = nblock + n0 + i;
        if (node < N_TAB) {
            float dv = dinv[node];   // dinv[N_NODES]=0 -> sentinel row zeros
            union { __half2 h[2]; float2 f; } u;
            u.h[0] = __floats2half2_rn(acc[i][0] * dv, acc[i][1] * dv);
            u.h[1] = __floats2half2_rn(acc[i][2] * dv, acc[i][3] * dv);
            *(float2*)(hs1 + ((size_t)(og >> 2) * N_TAB + node) * 16 + (og & 3) * 4) = u.f;
        }
    }
}

// ---------------- aggregate layer 1: XCD-pinned chunk passes ----------------
// chunk = bid & 3: with round-robin bid%8 -> XCD mapping, chunk c runs only on
// XCDs {c, c+4}, so each XCD keeps exactly ONE 3.2MB table L2-resident.
// csr stream + output stores are nontemporal so they don't evict the table.
// wave = 8 nodes (slot) x 8 featpairs (fp); no cross-lane reduction.
__global__ __launch_bounds__(256) void k_agg1(const __half* __restrict__ hs1,
                                              const int* __restrict__ csr,
                                              const int* __restrict__ rowstart,
                                              const float* __restrict__ dinv,
                                              const float* __restrict__ b1,
                                              float* __restrict__ out1) {
    int bid = blockIdx.x;            // grid = 12500
    int chunk = bid & 3;
    int nb = bid >> 2;               // 0..3124
    int w = threadIdx.x >> 6, lane = threadIdx.x & 63;
    int slot = lane >> 3, fp = lane & 7;
    int n = nb * 32 + w * 8 + slot;  // 3125*32 = 100000 exact
    const char* T = (const char*)(hs1 + (size_t)chunk * ((size_t)N_TAB * 16));
    unsigned fo = fp * 4u;
    int q0 = rowstart[n] >> 2, q1 = rowstart[n + 1] >> 2;
    h2v accA = {(_Float16)0.f, (_Float16)0.f};
    h2v accB = {(_Float16)0.f, (_Float16)0.f};
    for (int q = q0; q < q1; ++q) {
        i4v c = __builtin_nontemporal_load((const i4v*)csr + q);
        accA += *(const h2v*)(T + ((unsigned)c.x * 32u + fo));
        accB += *(const h2v*)(T + ((unsigned)c.y * 32u + fo));
        accA += *(const h2v*)(T + ((unsigned)c.z * 32u + fo));
        accB += *(const h2v*)(T + ((unsigned)c.w * 32u + fo));
    }
    h2v self = *(const h2v*)(T + ((unsigned)n * 32u + fo));
    float dv = dinv[n];
    int fb = chunk * 16 + fp * 2;
    float sx = (float)accA.x + (float)accB.x + (float)self.x;
    float sy = (float)accA.y + (float)accB.y + (float)self.y;
    f2v o = {fmaxf(dv * sx + b1[fb], 0.f), fmaxf(dv * sy + b1[fb + 1], 0.f)};
    __builtin_nontemporal_store(o, (f2v*)(out1 + (size_t)n * F_HID + fb));
}

// ---------------- GEMM2: hs2 = (out1 @ W2) * dinv, fp16, W2 in LDS ----------
__global__ __launch_bounds__(256) void k_gemm2(const float* __restrict__ h,
                                               const float* __restrict__ W2,
                                               const float* __restrict__ dinv,
                                               __half* __restrict__ hs2) {
    __shared__ float ws[F_HID * F_OUT];
    int t = threadIdx.x;
    ((float4*)ws)[t] = ((const float4*)W2)[t];
    __syncthreads();
    int tid = blockIdx.x * 256 + t;
    int n = tid >> 2;
    if (n > N_NODES) return;
    int cq = (tid & 3) << 2;
    if (n == N_NODES) {   // sentinel zero row
        *(float2*)(hs2 + (size_t)n * F_OUT + cq) = make_float2(0.f, 0.f);
        return;
    }
    const float4* h4 = (const float4*)(h + (size_t)n * F_HID);
    float4 acc = make_float4(0.f, 0.f, 0.f, 0.f);
#pragma unroll 4
    for (int k4 = 0; k4 < 16; ++k4) {
        float4 hv = h4[k4];
        float4 w0 = *(const float4*)(ws + (k4 * 4 + 0) * F_OUT + cq);
        float4 w1 = *(const float4*)(ws + (k4 * 4 + 1) * F_OUT + cq);
        float4 w2 = *(const float4*)(ws + (k4 * 4 + 2) * F_OUT + cq);
        float4 w3 = *(const float4*)(ws + (k4 * 4 + 3) * F_OUT + cq);
        acc.x += hv.x * w0.x + hv.y * w1.x + hv.z * w2.x + hv.w * w3.x;
        acc.y += hv.x * w0.y + hv.y * w1.y + hv.z * w2.y + hv.w * w3.y;
        acc.z += hv.x * w0.z + hv.y * w1.z + hv.z * w2.z + hv.w * w3.z;
        acc.w += hv.x * w0.w + hv.y * w1.w + hv.z * w2.w + hv.w * w3.w;
    }
    float dv = dinv[n];
    union { __half2 h2[2]; float2 f; } u;
    u.h2[0] = __floats2half2_rn(acc.x * dv, acc.y * dv);
    u.h2[1] = __floats2half2_rn(acc.z * dv, acc.w * dv);
    *(float2*)(hs2 + (size_t)n * F_OUT + cq) = u.f;
}

// ---------------- aggregate layer 2: single pass, slot=node layout ----------
__global__ __launch_bounds__(256) void k_agg2(const __half* __restrict__ hs2,
                                              const int* __restrict__ csr,
                                              const int* __restrict__ rowstart,
                                              const float* __restrict__ dinv,
                                              const float* __restrict__ b2,
                                              float* __restrict__ out) {
    int w = threadIdx.x >> 6, lane = threadIdx.x & 63;
    int slot = lane >> 3, fp = lane & 7;
    int n = blockIdx.x * 32 + w * 8 + slot;   // grid = 3125
    const char* T = (const char*)hs2;
    unsigned fo = fp * 4u;
    int q0 = rowstart[n] >> 2, q1 = rowstart[n + 1] >> 2;
    h2v accA = {(_Float16)0.f, (_Float16)0.f};
    h2v accB = {(_Float16)0.f, (_Float16)0.f};
    for (int q = q0; q < q1; ++q) {
        i4v c = __builtin_nontemporal_load((const i4v*)csr + q);
        accA += *(const h2v*)(T + ((unsigned)c.x * 32u + fo));
        accB += *(const h2v*)(T + ((unsigned)c.y * 32u + fo));
        accA += *(const h2v*)(T + ((unsigned)c.z * 32u + fo));
        accB += *(const h2v*)(T + ((unsigned)c.w * 32u + fo));
    }
    h2v self = *(const h2v*)(T + ((unsigned)n * 32u + fo));
    float dv = dinv[n];
    int fb = fp * 2;
    float sx = (float)accA.x + (float)accB.x + (float)self.x;
    float sy = (float)accA.y + (float)accB.y + (float)self.y;
    f2v o = {dv * sx + b2[fb], dv * sy + b2[fb + 1]};
    __builtin_nontemporal_store(o, (f2v*)(out + (size_t)n * F_OUT + fb));
}

extern "C" void kernel_launch(void* const* d_in, const int* in_sizes, int n_in,
                              void* d_out, int out_size, void* d_ws, size_t ws_size,
                              hipStream_t stream) {
    const float* x  = (const float*)d_in[0];
    const void*  ei = d_in[1];
    const float* W1 = (const float*)d_in[2];
    const float* b1 = (const float*)d_in[3];
    const float* W2 = (const float*)d_in[4];
    const float* b2 = (const float*)d_in[5];
    float* out = (float*)d_out;

    char* ws = (char*)d_ws;
    int*      cnt      = (int*)(ws + OFF_CNT);
    int*      rowstart = (int*)(ws + OFF_ROWSTART);
    float*    dinv     = (float*)(ws + OFF_DINV);
    int*      bsum     = (int*)(ws + OFF_BSUM);
    int*      flag     = (int*)(ws + OFF_FLAG);
    int*      bstart   = (int*)(ws + OFF_BSTART);
    int*      btot     = (int*)(ws + OFF_BTOT);
    int*      bhist    = (int*)(ws + OFF_BHIST);
    int*      csr      = (int*)(ws + OFF_CSR);
    __half*   hs1      = (__half*)(ws + OFF_HS1);
    float*    out1     = (float*)(ws + OFF_OUT1);
    __half*   hs2      = (__half*)(ws + OFF_HS2);
    unsigned* pairs    = (unsigned*)(ws + OFF_PAIRS);

    k_detect<<<1, 1, 0, stream>>>(ei, flag);

    // CSR build (padded rows, sentinel = N_NODES)
    k_bhist    <<<NBLK_P, 256, 0, stream>>>(ei, flag, bhist);
    k_btotal   <<<NBUCK, 128, 0, stream>>>(bhist, btot);
    k_bscan    <<<1, 512, 0, stream>>>(btot, bstart);
    k_boffs    <<<NBUCK, 512, 0, stream>>>(bhist, bstart);
    k_partition<<<NBLK_P, 256, 0, stream>>>(ei, flag, bhist, pairs);
    k_dcount   <<<NBUCK, 256, 0, stream>>>(pairs, bstart, cnt, dinv);
    k_scan_partial<<<98, 256, 0, stream>>>(cnt, bsum);
    k_scan_bsums  <<<1, 128, 0, stream>>>(bsum);
    k_scan_final  <<<98, 256, 0, stream>>>(cnt, bsum, rowstart);
    k_place    <<<NBUCK, 256, 0, stream>>>(pairs, bstart, rowstart, csr);

    // GCN layers
    k_gemm1<<<G1_BLOCKS, 256, 0, stream>>>(x, W1, dinv, hs1);
    k_agg1 <<<12500, 256, 0, stream>>>(hs1, csr, rowstart, dinv, b1, out1);
    k_gemm2<<<(N_TAB * 4 + 255) / 256, 256, 0, stream>>>(out1, W2, dinv, hs2);
    k_agg2 <<<3125, 256, 0, stream>>>(hs2, csr, rowstart, dinv, b2, out);
}

// Round 9
// 359.265 us; speedup vs baseline: 1.1723x; 1.1723x over previous
//
#include <hip/hip_runtime.h>
#include <hip/hip_fp16.h>
#include <stdint.h>

#define N_NODES   100000
#define N_TAB     (N_NODES + 1)   // +1 sentinel zero-row for CSR padding
#define N_EDGES   3200000
#define F_IN      128
#define F_HID     64
#define F_OUT     16

typedef _Float16 h2v __attribute__((ext_vector_type(2)));
typedef int   i4v __attribute__((ext_vector_type(4)));

// bucket partition params
#define BSHIFT    8
#define NBUCK     391                  // ceil(100000 / 256)
#define NBLK_P    512                  // partition blocks
#define CHUNK_E   (N_EDGES / NBLK_P)   // 6250 edges per block
#define PSTRIDE   9216                 // bucket region capacity (mean 8192 + 11 sigma)

// gemm1 tiling
#define G1_TM     128
#define G1_BLOCKS ((N_TAB + G1_TM - 1) / G1_TM)   // 782
#define XS_LD     132

// ---- workspace layout (bytes), 16B-aligned ----
#define OFF_CNT      0                 // int[N]
#define OFF_ROWSTART 400000            // int[N+1] (padded rowstarts, mult of 4)
#define OFF_DINV     800016            // float[N+1]
#define OFF_BSUM     1200032           // int[128]
#define OFF_GCNT     1200544           // int[NBUCK]
#define OFF_CSR      1202128           // int[3.5M]
#define OFF_HS1      15202128          // half[4][N_TAB][16]  (chunk-major)
#define OFF_OUT1     28002272          // float[N*64]
#define OFF_HS2      53602272          // half[N_TAB*16]
#define OFF_PAIRS    OFF_OUT1          // uint[NBUCK*PSTRIDE] = 14.4MB, aliases out1
// total ~56.9 MB

__device__ __forceinline__ int edge_src(const void* ei, int is64, int e) {
    return is64 ? (int)((const long long*)ei)[e] : ((const int*)ei)[e];
}
__device__ __forceinline__ int edge_dst(const void* ei, int is64, int e) {
    return is64 ? (int)((const long long*)ei)[N_EDGES + e]
                : ((const int*)ei)[N_EDGES + e];
}

// ---- pass 1: partition edges into fixed-capacity bucket regions ------------
// Per-block: inline dtype detect (thread 0), LDS bucket histogram, one global
// atomicAdd per bucket to reserve a range, then scatter (src<<8|dloc) pairs.
__global__ __launch_bounds__(256) void k_partition(const void* __restrict__ ei,
                                                   int* __restrict__ gcnt,
                                                   unsigned* __restrict__ pairs) {
    __shared__ int h[NBUCK];
    __shared__ int cur[NBUCK];
    __shared__ int is64s;
    int t = threadIdx.x;
    if (t == 0) {
        // int64 data viewed as u32 pairs: [lo<100000, hi==0] x 64. For int32
        // data the hi words are random node ids: P(all zero) ~ 0.
        const unsigned* u = (const unsigned*)ei;
        int ok = 1;
        for (int i = 0; i < 64; ++i) {
            unsigned lo = u[2 * i], hi = u[2 * i + 1];
            if (hi != 0u || lo >= 100000u) { ok = 0; break; }
        }
        is64s = ok;
    }
    for (int i = t; i < NBUCK; i += 256) h[i] = 0;
    __syncthreads();
    int is64 = is64s;
    int base = blockIdx.x * CHUNK_E;
    for (int i = t; i < CHUNK_E; i += 256)
        atomicAdd(&h[edge_dst(ei, is64, base + i) >> BSHIFT], 1);
    __syncthreads();
    for (int i = t; i < NBUCK; i += 256) {
        int c = h[i];
        cur[i] = c ? atomicAdd(&gcnt[i], c) : 0;
    }
    __syncthreads();
    for (int i = t; i < CHUNK_E; i += 256) {
        int e = base + i;
        int s = edge_src(ei, is64, e);
        int d = edge_dst(ei, is64, e);
        int b = d >> BSHIFT;
        int p = atomicAdd(&cur[b], 1);
        if (p < PSTRIDE)   // statistically impossible to overflow; guard anyway
            pairs[b * PSTRIDE + p] = ((unsigned)s << 8) | (unsigned)(d & 255);
    }
}

// ---- pass 2: per-bucket dst counts + dinv ----------------------------------
__global__ __launch_bounds__(512) void k_dcount(const unsigned* __restrict__ pairs,
                                                const int* __restrict__ gcnt,
                                                int* __restrict__ cnt,
                                                float* __restrict__ dinv) {
    __shared__ int c[256];
    int b = blockIdx.x, t = threadIdx.x;
    if (t < 256) c[t] = 0;
    __syncthreads();
    int tot = gcnt[b]; if (tot > PSTRIDE) tot = PSTRIDE;
    int base = b * PSTRIDE;
    for (int i = t; i < tot; i += 512)
        atomicAdd(&c[pairs[base + i] & 255u], 1);
    __syncthreads();
    if (t < 256) {
        int d = (b << BSHIFT) + t;
        if (d < N_NODES) {
            cnt[d] = c[t];
            dinv[d] = rsqrtf((float)c[t] + 1.0f);
        } else if (d == N_NODES) {
            dinv[d] = 0.f;   // sentinel
        }
    }
}

// ---- exclusive scan of PADDED cnt -> rowstart ------------------------------
__global__ __launch_bounds__(256) void k_scan_partial(const int* __restrict__ cnt,
                                                      int* __restrict__ bsum) {
    __shared__ int sd[256];
    int t = threadIdx.x;
    int base = blockIdx.x * 1024 + t * 4;
    int s = 0;
#pragma unroll
    for (int c = 0; c < 4; ++c)
        if (base + c < N_NODES) s += (cnt[base + c] + 3) & ~3;
    sd[t] = s;
    __syncthreads();
    for (int off = 128; off > 0; off >>= 1) {
        if (t < off) sd[t] += sd[t + off];
        __syncthreads();
    }
    if (t == 0) bsum[blockIdx.x] = sd[0];
}

__global__ void k_scan_bsums(int* __restrict__ bsum) {  // <<<1,128>>>, NB=98
    __shared__ int sd[128];
    int t = threadIdx.x;
    sd[t] = (t < 98) ? bsum[t] : 0;
    __syncthreads();
    for (int off = 1; off < 128; off <<= 1) {
        int add = (t >= off) ? sd[t - off] : 0;
        __syncthreads();
        sd[t] += add;
        __syncthreads();
    }
    if (t < 98) bsum[t] = (t == 0) ? 0 : sd[t - 1];
}

__global__ __launch_bounds__(256) void k_scan_final(const int* __restrict__ cnt,
                                                    const int* __restrict__ bsum,
                                                    int* __restrict__ rowstart) {
    __shared__ int sd[256];
    int t = threadIdx.x;
    int base = blockIdx.x * 1024 + t * 4;
    int v[4];
#pragma unroll
    for (int c = 0; c < 4; ++c)
        v[c] = (base + c < N_NODES) ? ((cnt[base + c] + 3) & ~3) : 0;
    int tsum = v[0] + v[1] + v[2] + v[3];
    sd[t] = tsum;
    __syncthreads();
    for (int off = 1; off < 256; off <<= 1) {
        int add = (t >= off) ? sd[t - off] : 0;
        __syncthreads();
        sd[t] += add;
        __syncthreads();
    }
    int run = bsum[blockIdx.x] + sd[t] - tsum;
#pragma unroll
    for (int c = 0; c < 4; ++c) {
        if (base + c < N_NODES) rowstart[base + c] = run;
        run += v[c];
        if (base + c == N_NODES - 1) rowstart[N_NODES] = run;
    }
}

// ---- pass 3: sentinel-fill + CSR placement ---------------------------------
__global__ __launch_bounds__(512) void k_place(const unsigned* __restrict__ pairs,
                                               const int* __restrict__ gcnt,
                                               const int* __restrict__ rowstart,
                                               int* __restrict__ csr) {
    __shared__ int pos[256];
    int b = blockIdx.x, t = threadIdx.x;
    int dbase = b << BSHIFT;
    if (t < 256) {
        int d = dbase + t;
        pos[t] = (d < N_NODES) ? rowstart[d] : 0;
    }
    int hiIdx = dbase + 256; if (hiIdx > N_NODES) hiIdx = N_NODES;
    int lo = rowstart[dbase], hi = rowstart[hiIdx];
    for (int i = lo + t; i < hi; i += 512) csr[i] = N_NODES;  // sentinel pad
    __syncthreads();
    int tot = gcnt[b]; if (tot > PSTRIDE) tot = PSTRIDE;
    int base = b * PSTRIDE;
    for (int i = base + t; i < base + tot; i += 512) {
        unsigned pr = pairs[i];
        int p = atomicAdd(&pos[pr & 255u], 1);
        csr[p] = (int)(pr >> 8);
    }
}

// ---- GEMM1 (LDS-tiled): hs1[chunk][node][16] = (x@W1)*dinv -----------------
__global__ __launch_bounds__(256) void k_gemm1(const float* __restrict__ x,
                                               const float* __restrict__ W1,
                                               const float* __restrict__ dinv,
                                               __half* __restrict__ hs1) {
    __shared__ float xsT[64 * XS_LD];
    __shared__ float ws[64 * 64];
    int t = threadIdx.x;
    int nblock = blockIdx.x * G1_TM;
    int ng = t >> 4, og = t & 15;
    int n0 = ng * 8;
    float acc[8][4] = {};

    int snode = nblock + (t >> 1);
    int koff = (t & 1) * 32;
    int nl = t >> 1;

    for (int chunk = 0; chunk < 2; ++chunk) {
        int kbase = chunk * 64;
        {
            float4 v[8];
            if (snode < N_NODES) {
                const float4* src = (const float4*)(x + (size_t)snode * F_IN + kbase + koff);
#pragma unroll
                for (int c = 0; c < 8; ++c) v[c] = src[c];
            } else {
#pragma unroll
                for (int c = 0; c < 8; ++c) v[c] = make_float4(0.f, 0.f, 0.f, 0.f);
            }
#pragma unroll
            for (int c = 0; c < 8; ++c) {
                int k = koff + c * 4;
                xsT[(k + 0) * XS_LD + nl] = v[c].x;
                xsT[(k + 1) * XS_LD + nl] = v[c].y;
                xsT[(k + 2) * XS_LD + nl] = v[c].z;
                xsT[(k + 3) * XS_LD + nl] = v[c].w;
            }
        }
        {
            const float4* wsrc = (const float4*)(W1 + kbase * F_HID);
            float4* wdst = (float4*)ws;
#pragma unroll
            for (int c = 0; c < 4; ++c) wdst[c * 256 + t] = wsrc[c * 256 + t];
        }
        __syncthreads();

#pragma unroll 4
        for (int k = 0; k < 64; ++k) {
            const float4* xr = (const float4*)(xsT + k * XS_LD + n0);
            float4 a0 = xr[0], a1 = xr[1];
            float4 bv = *(const float4*)(ws + k * 64 + og * 4);
            float a[8] = {a0.x, a0.y, a0.z, a0.w, a1.x, a1.y, a1.z, a1.w};
            float bb[4] = {bv.x, bv.y, bv.z, bv.w};
#pragma unroll
            for (int i = 0; i < 8; ++i)
#pragma unroll
                for (int j = 0; j < 4; ++j)
                    acc[i][j] += a[i] * bb[j];
        }
        __syncthreads();
    }

#pragma unroll
    for (int i = 0; i < 8; ++i) {
        int node = nblock + n0 + i;
        if (node < N_TAB) {
            float dv = dinv[node];   // dinv[N_NODES]=0 -> sentinel row zeros
            union { __half2 h[2]; float2 f; } u;
            u.h[0] = __floats2half2_rn(acc[i][0] * dv, acc[i][1] * dv);
            u.h[1] = __floats2half2_rn(acc[i][2] * dv, acc[i][3] * dv);
            *(float2*)(hs1 + ((size_t)(og >> 2) * N_TAB + node) * 16 + (og & 3) * 4) = u.f;
        }
    }
}

// ---- aggregate layer 1: 4 temporally-phased L2-resident chunk passes -------
// chunk = bid/3125 (R6 config — measured best). wave = 8 nodes x 8 featpairs.
// Unroll-by-2 with 4 fp16x2 accumulators: 8 gathers in flight, short chains.
__global__ __launch_bounds__(256) void k_agg1(const __half* __restrict__ hs1,
                                              const int* __restrict__ csr,
                                              const int* __restrict__ rowstart,
                                              const float* __restrict__ dinv,
                                              const float* __restrict__ b1,
                                              float* __restrict__ out1) {
    int bid = blockIdx.x;            // grid = 4 * 3125
    int chunk = bid / 3125;
    int nb = bid - chunk * 3125;
    int w = threadIdx.x >> 6, lane = threadIdx.x & 63;
    int slot = lane >> 3, fp = lane & 7;
    int n = nb * 32 + w * 8 + slot;  // 3125*32 = 100000 exact
    const char* T = (const char*)(hs1 + (size_t)chunk * ((size_t)N_TAB * 16));
    unsigned fo = fp * 4u;
    int q0 = rowstart[n] >> 2, q1 = rowstart[n + 1] >> 2;
    const i4v* Q = (const i4v*)csr;
    h2v a0 = {(_Float16)0.f, (_Float16)0.f};
    h2v a1 = a0, a2 = a0, a3 = a0;
    int q = q0;
    for (; q + 2 <= q1; q += 2) {
        i4v c0 = Q[q], c1 = Q[q + 1];
        a0 += *(const h2v*)(T + ((unsigned)c0.x * 32u + fo));
        a1 += *(const h2v*)(T + ((unsigned)c0.y * 32u + fo));
        a2 += *(const h2v*)(T + ((unsigned)c0.z * 32u + fo));
        a3 += *(const h2v*)(T + ((unsigned)c0.w * 32u + fo));
        a0 += *(const h2v*)(T + ((unsigned)c1.x * 32u + fo));
        a1 += *(const h2v*)(T + ((unsigned)c1.y * 32u + fo));
        a2 += *(const h2v*)(T + ((unsigned)c1.z * 32u + fo));
        a3 += *(const h2v*)(T + ((unsigned)c1.w * 32u + fo));
    }
    if (q < q1) {
        i4v c0 = Q[q];
        a0 += *(const h2v*)(T + ((unsigned)c0.x * 32u + fo));
        a1 += *(const h2v*)(T + ((unsigned)c0.y * 32u + fo));
        a2 += *(const h2v*)(T + ((unsigned)c0.z * 32u + fo));
        a3 += *(const h2v*)(T + ((unsigned)c0.w * 32u + fo));
    }
    h2v self = *(const h2v*)(T + ((unsigned)n * 32u + fo));
    float dv = dinv[n];
    int fb = chunk * 16 + fp * 2;
    float sx = ((float)a0.x + (float)a1.x) + ((float)a2.x + (float)a3.x) + (float)self.x;
    float sy = ((float)a0.y + (float)a1.y) + ((float)a2.y + (float)a3.y) + (float)self.y;
    float ox = fmaxf(dv * sx + b1[fb], 0.f);
    float oy = fmaxf(dv * sy + b1[fb + 1], 0.f);
    *(float2*)(out1 + (size_t)n * F_HID + fb) = make_float2(ox, oy);
}

// ---- GEMM2: hs2 = (out1 @ W2) * dinv, fp16, W2 in LDS ----------------------
__global__ __launch_bounds__(256) void k_gemm2(const float* __restrict__ h,
                                               const float* __restrict__ W2,
                                               const float* __restrict__ dinv,
                                               __half* __restrict__ hs2) {
    __shared__ float ws[F_HID * F_OUT];
    int t = threadIdx.x;
    ((float4*)ws)[t] = ((const float4*)W2)[t];
    __syncthreads();
    int tid = blockIdx.x * 256 + t;
    int n = tid >> 2;
    if (n > N_NODES) return;
    int cq = (tid & 3) << 2;
    if (n == N_NODES) {   // sentinel zero row
        *(float2*)(hs2 + (size_t)n * F_OUT + cq) = make_float2(0.f, 0.f);
        return;
    }
    const float4* h4 = (const float4*)(h + (size_t)n * F_HID);
    float4 acc = make_float4(0.f, 0.f, 0.f, 0.f);
#pragma unroll 4
    for (int k4 = 0; k4 < 16; ++k4) {
        float4 hv = h4[k4];
        float4 w0 = *(const float4*)(ws + (k4 * 4 + 0) * F_OUT + cq);
        float4 w1 = *(const float4*)(ws + (k4 * 4 + 1) * F_OUT + cq);
        float4 w2 = *(const float4*)(ws + (k4 * 4 + 2) * F_OUT + cq);
        float4 w3 = *(const float4*)(ws + (k4 * 4 + 3) * F_OUT + cq);
        acc.x += hv.x * w0.x + hv.y * w1.x + hv.z * w2.x + hv.w * w3.x;
        acc.y += hv.x * w0.y + hv.y * w1.y + hv.z * w2.y + hv.w * w3.y;
        acc.z += hv.x * w0.z + hv.y * w1.z + hv.z * w2.z + hv.w * w3.z;
        acc.w += hv.x * w0.w + hv.y * w1.w + hv.z * w2.w + hv.w * w3.w;
    }
    float dv = dinv[n];
    union { __half2 h2[2]; float2 f; } u;
    u.h2[0] = __floats2half2_rn(acc.x * dv, acc.y * dv);
    u.h2[1] = __floats2half2_rn(acc.z * dv, acc.w * dv);
    *(float2*)(hs2 + (size_t)n * F_OUT + cq) = u.f;
}

// ---- aggregate layer 2: single pass (3.2MB table), unroll-by-2 -------------
__global__ __launch_bounds__(256) void k_agg2(const __half* __restrict__ hs2,
                                              const int* __restrict__ csr,
                                              const int* __restrict__ rowstart,
                                              const float* __restrict__ dinv,
                                              const float* __restrict__ b2,
                                              float* __restrict__ out) {
    int w = threadIdx.x >> 6, lane = threadIdx.x & 63;
    int slot = lane >> 3, fp = lane & 7;
    int n = blockIdx.x * 32 + w * 8 + slot;   // grid = 3125
    const char* T = (const char*)hs2;
    unsigned fo = fp * 4u;
    int q0 = rowstart[n] >> 2, q1 = rowstart[n + 1] >> 2;
    const i4v* Q = (const i4v*)csr;
    h2v a0 = {(_Float16)0.f, (_Float16)0.f};
    h2v a1 = a0, a2 = a0, a3 = a0;
    int q = q0;
    for (; q + 2 <= q1; q += 2) {
        i4v c0 = Q[q], c1 = Q[q + 1];
        a0 += *(const h2v*)(T + ((unsigned)c0.x * 32u + fo));
        a1 += *(const h2v*)(T + ((unsigned)c0.y * 32u + fo));
        a2 += *(const h2v*)(T + ((unsigned)c0.z * 32u + fo));
        a3 += *(const h2v*)(T + ((unsigned)c0.w * 32u + fo));
        a0 += *(const h2v*)(T + ((unsigned)c1.x * 32u + fo));
        a1 += *(const h2v*)(T + ((unsigned)c1.y * 32u + fo));
        a2 += *(const h2v*)(T + ((unsigned)c1.z * 32u + fo));
        a3 += *(const h2v*)(T + ((unsigned)c1.w * 32u + fo));
    }
    if (q < q1) {
        i4v c0 = Q[q];
        a0 += *(const h2v*)(T + ((unsigned)c0.x * 32u + fo));
        a1 += *(const h2v*)(T + ((unsigned)c0.y * 32u + fo));
        a2 += *(const h2v*)(T + ((unsigned)c0.z * 32u + fo));
        a3 += *(const h2v*)(T + ((unsigned)c0.w * 32u + fo));
    }
    h2v self = *(const h2v*)(T + ((unsigned)n * 32u + fo));
    float dv = dinv[n];
    int fb = fp * 2;
    float sx = ((float)a0.x + (float)a1.x) + ((float)a2.x + (float)a3.x) + (float)self.x;
    float sy = ((float)a0.y + (float)a1.y) + ((float)a2.y + (float)a3.y) + (float)self.y;
    float ox = dv * sx + b2[fb];
    float oy = dv * sy + b2[fb + 1];
    *(float2*)(out + (size_t)n * F_OUT + fb) = make_float2(ox, oy);
}

extern "C" void kernel_launch(void* const* d_in, const int* in_sizes, int n_in,
                              void* d_out, int out_size, void* d_ws, size_t ws_size,
                              hipStream_t stream) {
    const float* x  = (const float*)d_in[0];
    const void*  ei = d_in[1];
    const float* W1 = (const float*)d_in[2];
    const float* b1 = (const float*)d_in[3];
    const float* W2 = (const float*)d_in[4];
    const float* b2 = (const float*)d_in[5];
    float* out = (float*)d_out;

    char* ws = (char*)d_ws;
    int*      cnt      = (int*)(ws + OFF_CNT);
    int*      rowstart = (int*)(ws + OFF_ROWSTART);
    float*    dinv     = (float*)(ws + OFF_DINV);
    int*      bsum     = (int*)(ws + OFF_BSUM);
    int*      gcnt     = (int*)(ws + OFF_GCNT);
    int*      csr      = (int*)(ws + OFF_CSR);
    __half*   hs1      = (__half*)(ws + OFF_HS1);
    float*    out1     = (float*)(ws + OFF_OUT1);
    __half*   hs2      = (__half*)(ws + OFF_HS2);
    unsigned* pairs    = (unsigned*)(ws + OFF_PAIRS);

    hipMemsetAsync(gcnt, 0, NBUCK * sizeof(int), stream);

    // CSR build (consolidated: 6 kernels)
    k_partition<<<NBLK_P, 256, 0, stream>>>(ei, gcnt, pairs);
    k_dcount   <<<NBUCK, 512, 0, stream>>>(pairs, gcnt, cnt, dinv);
    k_scan_partial<<<98, 256, 0, stream>>>(cnt, bsum);
    k_scan_bsums  <<<1, 128, 0, stream>>>(bsum);
    k_scan_final  <<<98, 256, 0, stream>>>(cnt, bsum, rowstart);
    k_place    <<<NBUCK, 512, 0, stream>>>(pairs, gcnt, rowstart, csr);

    // GCN layers
    k_gemm1<<<G1_BLOCKS, 256, 0, stream>>>(x, W1, dinv, hs1);
    k_agg1 <<<4 * 3125, 256, 0, stream>>>(hs1, csr, rowstart, dinv, b1, out1);
    k_gemm2<<<(N_TAB * 4 + 255) / 256, 256, 0, stream>>>(out1, W2, dinv, hs2);
    k_agg2 <<<3125, 256, 0, stream>>>(hs2, csr, rowstart, dinv, b2, out);
}

// Round 10
// 342.245 us; speedup vs baseline: 1.2306x; 1.0497x over previous
//
#include <hip/hip_runtime.h>
#include <hip/hip_fp16.h>
#include <stdint.h>

#define N_NODES   100000
#define N_TAB     (N_NODES + 1)   // +1 sentinel zero-row for CSR padding
#define N_EDGES   3200000
#define F_IN      128
#define F_HID     64
#define F_OUT     16

typedef _Float16 h2v __attribute__((ext_vector_type(2)));
typedef int   i4v __attribute__((ext_vector_type(4)));

// bucket partition params
#define BSHIFT    8
#define NBUCK     391                  // ceil(100000 / 256)
#define NBLK_P    512                  // partition blocks
#define CHUNK_E   (N_EDGES / NBLK_P)   // 6250 edges per block
#define PSTRIDE   9472                 // bucket region capacity (mean padded 8576 + ~10 sigma), mult of 4

// gemm1 tiling
#define G1_TM     128
#define G1_BLOCKS ((N_TAB + G1_TM - 1) / G1_TM)   // 782
#define XS_LD     132

// ---- workspace layout (bytes), 16B-aligned ----
#define OFF_RE       0                 // int[N]    rowend (padded) per node
#define OFF_RS       400000            // int[N]    rowstart per node (bucket-local CSR)
#define OFF_DINV     800000            // float[N+1]
#define OFF_GCNT     1200016           // int[NBUCK]
#define OFF_CSR      1201616           // int[NBUCK*PSTRIDE] = 14,814,208 B
#define OFF_HS1      16015824          // half[4][N_TAB][16]  (chunk-major) = 12,800,128 B
#define OFF_OUT1     28815952          // float[N*64] = 25.6 MB
#define OFF_HS2      54415952          // half[N_TAB*16]
#define OFF_PAIRS    OFF_OUT1          // uint[NBUCK*PSTRIDE] = 14.8 MB, aliases out1
// total ~57.6 MB

__device__ __forceinline__ int edge_src(const void* ei, int is64, int e) {
    return is64 ? (int)((const long long*)ei)[e] : ((const int*)ei)[e];
}
__device__ __forceinline__ int edge_dst(const void* ei, int is64, int e) {
    return is64 ? (int)((const long long*)ei)[N_EDGES + e]
                : ((const int*)ei)[N_EDGES + e];
}

// ---- pass 1: partition edges into fixed-capacity bucket regions ------------
__global__ __launch_bounds__(256) void k_partition(const void* __restrict__ ei,
                                                   int* __restrict__ gcnt,
                                                   unsigned* __restrict__ pairs) {
    __shared__ int h[NBUCK];
    __shared__ int cur[NBUCK];
    __shared__ int is64s;
    int t = threadIdx.x;
    if (t == 0) {
        // int64 data viewed as u32 pairs: [lo<100000, hi==0] x 64. For int32
        // data the hi words are random node ids: P(all zero) ~ 0.
        const unsigned* u = (const unsigned*)ei;
        int ok = 1;
        for (int i = 0; i < 64; ++i) {
            unsigned lo = u[2 * i], hi = u[2 * i + 1];
            if (hi != 0u || lo >= 100000u) { ok = 0; break; }
        }
        is64s = ok;
    }
    for (int i = t; i < NBUCK; i += 256) h[i] = 0;
    __syncthreads();
    int is64 = is64s;
    int base = blockIdx.x * CHUNK_E;
    for (int i = t; i < CHUNK_E; i += 256)
        atomicAdd(&h[edge_dst(ei, is64, base + i) >> BSHIFT], 1);
    __syncthreads();
    for (int i = t; i < NBUCK; i += 256) {
        int c = h[i];
        cur[i] = c ? atomicAdd(&gcnt[i], c) : 0;
    }
    __syncthreads();
    for (int i = t; i < CHUNK_E; i += 256) {
        int e = base + i;
        int s = edge_src(ei, is64, e);
        int d = edge_dst(ei, is64, e);
        int b = d >> BSHIFT;
        int p = atomicAdd(&cur[b], 1);
        if (p < PSTRIDE)   // statistically impossible to overflow; guard anyway
            pairs[b * PSTRIDE + p] = ((unsigned)s << 8) | (unsigned)(d & 255);
    }
}

// ---- pass 2: per-bucket count + scan + dinv + CSR place (single kernel) ----
// Bucket-local CSR: node rows live inside bucket b's [b*PSTRIDE, ...) region,
// quad-padded with sentinel N_NODES. rowstart/rowend are absolute indices.
__global__ __launch_bounds__(512) void k_build(const unsigned* __restrict__ pairs,
                                               const int* __restrict__ gcnt,
                                               int* __restrict__ rowstart,
                                               int* __restrict__ rowend,
                                               float* __restrict__ dinv,
                                               int* __restrict__ csr) {
    __shared__ int cntS[256], scanS[256], posS[256];
    int b = blockIdx.x, t = threadIdx.x;
    if (t < 256) cntS[t] = 0;
    __syncthreads();
    int tot = gcnt[b]; if (tot > PSTRIDE) tot = PSTRIDE;
    int base = b * PSTRIDE;
    for (int i = t; i < tot; i += 512)
        atomicAdd(&cntS[pairs[base + i] & 255u], 1);
    __syncthreads();
    int padded = 0;
    if (t < 256) { padded = (cntS[t] + 3) & ~3; scanS[t] = padded; }
    __syncthreads();
    for (int off = 1; off < 256; off <<= 1) {
        int add = 0;
        if (t < 256 && t >= off) add = scanS[t - off];
        __syncthreads();
        if (t < 256) scanS[t] += add;
        __syncthreads();
    }
    if (t < 256) {
        int rs = base + scanS[t] - padded;   // exclusive scan, quad-aligned
        posS[t] = rs;
        int d = (b << BSHIFT) + t;
        if (d < N_NODES) {
            rowstart[d] = rs;
            rowend[d]   = rs + padded;
            dinv[d] = rsqrtf((float)cntS[t] + 1.0f);
            for (int j = cntS[t]; j < padded; ++j) csr[rs + j] = N_NODES; // pad
        } else if (d == N_NODES) {
            dinv[d] = 0.f;   // sentinel
        }
    }
    __syncthreads();
    for (int i = t; i < tot; i += 512) {
        unsigned pr = pairs[base + i];
        int p = atomicAdd(&posS[pr & 255u], 1);
        csr[p] = (int)(pr >> 8);
    }
}

// ---- GEMM1 (LDS-tiled): hs1[chunk][node][16] = (x@W1)*dinv -----------------
__global__ __launch_bounds__(256) void k_gemm1(const float* __restrict__ x,
                                               const float* __restrict__ W1,
                                               const float* __restrict__ dinv,
                                               __half* __restrict__ hs1) {
    __shared__ float xsT[64 * XS_LD];
    __shared__ float ws[64 * 64];
    int t = threadIdx.x;
    int nblock = blockIdx.x * G1_TM;
    int ng = t >> 4, og = t & 15;
    int n0 = ng * 8;
    float acc[8][4] = {};

    int snode = nblock + (t >> 1);
    int koff = (t & 1) * 32;
    int nl = t >> 1;

    for (int chunk = 0; chunk < 2; ++chunk) {
        int kbase = chunk * 64;
        {
            float4 v[8];
            if (snode < N_NODES) {
                const float4* src = (const float4*)(x + (size_t)snode * F_IN + kbase + koff);
#pragma unroll
                for (int c = 0; c < 8; ++c) v[c] = src[c];
            } else {
#pragma unroll
                for (int c = 0; c < 8; ++c) v[c] = make_float4(0.f, 0.f, 0.f, 0.f);
            }
#pragma unroll
            for (int c = 0; c < 8; ++c) {
                int k = koff + c * 4;
                xsT[(k + 0) * XS_LD + nl] = v[c].x;
                xsT[(k + 1) * XS_LD + nl] = v[c].y;
                xsT[(k + 2) * XS_LD + nl] = v[c].z;
                xsT[(k + 3) * XS_LD + nl] = v[c].w;
            }
        }
        {
            const float4* wsrc = (const float4*)(W1 + kbase * F_HID);
            float4* wdst = (float4*)ws;
#pragma unroll
            for (int c = 0; c < 4; ++c) wdst[c * 256 + t] = wsrc[c * 256 + t];
        }
        __syncthreads();

#pragma unroll 4
        for (int k = 0; k < 64; ++k) {
            const float4* xr = (const float4*)(xsT + k * XS_LD + n0);
            float4 a0 = xr[0], a1 = xr[1];
            float4 bv = *(const float4*)(ws + k * 64 + og * 4);
            float a[8] = {a0.x, a0.y, a0.z, a0.w, a1.x, a1.y, a1.z, a1.w};
            float bb[4] = {bv.x, bv.y, bv.z, bv.w};
#pragma unroll
            for (int i = 0; i < 8; ++i)
#pragma unroll
                for (int j = 0; j < 4; ++j)
                    acc[i][j] += a[i] * bb[j];
        }
        __syncthreads();
    }

#pragma unroll
    for (int i = 0; i < 8; ++i) {
        int node = nblock + n0 + i;
        if (node < N_TAB) {
            float dv = dinv[node];   // dinv[N_NODES]=0 -> sentinel row zeros
            union { __half2 h[2]; float2 f; } u;
            u.h[0] = __floats2half2_rn(acc[i][0] * dv, acc[i][1] * dv);
            u.h[1] = __floats2half2_rn(acc[i][2] * dv, acc[i][3] * dv);
            *(float2*)(hs1 + ((size_t)(og >> 2) * N_TAB + node) * 16 + (og & 3) * 4) = u.f;
        }
    }
}

// ---- aggregate layer 1: XCD-pinned chunk passes (NO nontemporal hints) -----
// chunk = bid & 3: with round-robin bid%8 -> XCD, chunk c runs on XCDs {c,c+4}
// only, so each XCD keeps exactly ONE 3.2MB table L2-resident (kills the 8x
// table replication seen with temporal phasing). csr/L1 locality preserved.
// wave = 8 nodes (slot) x 8 featpairs; unroll-2, 4 fp16x2 accumulators.
__global__ __launch_bounds__(256) void k_agg1(const __half* __restrict__ hs1,
                                              const int* __restrict__ csr,
                                              const int* __restrict__ rowstart,
                                              const int* __restrict__ rowend,
                                              const float* __restrict__ dinv,
                                              const float* __restrict__ b1,
                                              float* __restrict__ out1) {
    int bid = blockIdx.x;            // grid = 12500
    int chunk = bid & 3;
    int nb = bid >> 2;               // 0..3124
    int w = threadIdx.x >> 6, lane = threadIdx.x & 63;
    int slot = lane >> 3, fp = lane & 7;
    int n = nb * 32 + w * 8 + slot;  // 3125*32 = 100000 exact
    const char* T = (const char*)(hs1 + (size_t)chunk * ((size_t)N_TAB * 16));
    unsigned fo = fp * 4u;
    int q0 = rowstart[n] >> 2, q1 = rowend[n] >> 2;
    const i4v* Q = (const i4v*)csr;
    h2v a0 = {(_Float16)0.f, (_Float16)0.f};
    h2v a1 = a0, a2 = a0, a3 = a0;
    int q = q0;
    for (; q + 2 <= q1; q += 2) {
        i4v c0 = Q[q], c1 = Q[q + 1];
        a0 += *(const h2v*)(T + ((unsigned)c0.x * 32u + fo));
        a1 += *(const h2v*)(T + ((unsigned)c0.y * 32u + fo));
        a2 += *(const h2v*)(T + ((unsigned)c0.z * 32u + fo));
        a3 += *(const h2v*)(T + ((unsigned)c0.w * 32u + fo));
        a0 += *(const h2v*)(T + ((unsigned)c1.x * 32u + fo));
        a1 += *(const h2v*)(T + ((unsigned)c1.y * 32u + fo));
        a2 += *(const h2v*)(T + ((unsigned)c1.z * 32u + fo));
        a3 += *(const h2v*)(T + ((unsigned)c1.w * 32u + fo));
    }
    if (q < q1) {
        i4v c0 = Q[q];
        a0 += *(const h2v*)(T + ((unsigned)c0.x * 32u + fo));
        a1 += *(const h2v*)(T + ((unsigned)c0.y * 32u + fo));
        a2 += *(const h2v*)(T + ((unsigned)c0.z * 32u + fo));
        a3 += *(const h2v*)(T + ((unsigned)c0.w * 32u + fo));
    }
    h2v self = *(const h2v*)(T + ((unsigned)n * 32u + fo));
    float dv = dinv[n];
    int fb = chunk * 16 + fp * 2;
    float sx = ((float)a0.x + (float)a1.x) + ((float)a2.x + (float)a3.x) + (float)self.x;
    float sy = ((float)a0.y + (float)a1.y) + ((float)a2.y + (float)a3.y) + (float)self.y;
    float ox = fmaxf(dv * sx + b1[fb], 0.f);
    float oy = fmaxf(dv * sy + b1[fb + 1], 0.f);
    *(float2*)(out1 + (size_t)n * F_HID + fb) = make_float2(ox, oy);
}

// ---- GEMM2: hs2 = (out1 @ W2) * dinv, fp16, W2 in LDS ----------------------
__global__ __launch_bounds__(256) void k_gemm2(const float* __restrict__ h,
                                               const float* __restrict__ W2,
                                               const float* __restrict__ dinv,
                                               __half* __restrict__ hs2) {
    __shared__ float ws[F_HID * F_OUT];
    int t = threadIdx.x;
    ((float4*)ws)[t] = ((const float4*)W2)[t];
    __syncthreads();
    int tid = blockIdx.x * 256 + t;
    int n = tid >> 2;
    if (n > N_NODES) return;
    int cq = (tid & 3) << 2;
    if (n == N_NODES) {   // sentinel zero row
        *(float2*)(hs2 + (size_t)n * F_OUT + cq) = make_float2(0.f, 0.f);
        return;
    }
    const float4* h4 = (const float4*)(h + (size_t)n * F_HID);
    float4 acc = make_float4(0.f, 0.f, 0.f, 0.f);
#pragma unroll 4
    for (int k4 = 0; k4 < 16; ++k4) {
        float4 hv = h4[k4];
        float4 w0 = *(const float4*)(ws + (k4 * 4 + 0) * F_OUT + cq);
        float4 w1 = *(const float4*)(ws + (k4 * 4 + 1) * F_OUT + cq);
        float4 w2 = *(const float4*)(ws + (k4 * 4 + 2) * F_OUT + cq);
        float4 w3 = *(const float4*)(ws + (k4 * 4 + 3) * F_OUT + cq);
        acc.x += hv.x * w0.x + hv.y * w1.x + hv.z * w2.x + hv.w * w3.x;
        acc.y += hv.x * w0.y + hv.y * w1.y + hv.z * w2.y + hv.w * w3.y;
        acc.z += hv.x * w0.z + hv.y * w1.z + hv.z * w2.z + hv.w * w3.z;
        acc.w += hv.x * w0.w + hv.y * w1.w + hv.z * w2.w + hv.w * w3.w;
    }
    float dv = dinv[n];
    union { __half2 h2[2]; float2 f; } u;
    u.h2[0] = __floats2half2_rn(acc.x * dv, acc.y * dv);
    u.h2[1] = __floats2half2_rn(acc.z * dv, acc.w * dv);
    *(float2*)(hs2 + (size_t)n * F_OUT + cq) = u.f;
}

// ---- aggregate layer 2: single pass (3.2MB table), unroll-by-2 -------------
__global__ __launch_bounds__(256) void k_agg2(const __half* __restrict__ hs2,
                                              const int* __restrict__ csr,
                                              const int* __restrict__ rowstart,
                                              const int* __restrict__ rowend,
                                              const float* __restrict__ dinv,
                                              const float* __restrict__ b2,
                                              float* __restrict__ out) {
    int w = threadIdx.x >> 6, lane = threadIdx.x & 63;
    int slot = lane >> 3, fp = lane & 7;
    int n = blockIdx.x * 32 + w * 8 + slot;   // grid = 3125
    const char* T = (const char*)hs2;
    unsigned fo = fp * 4u;
    int q0 = rowstart[n] >> 2, q1 = rowend[n] >> 2;
    const i4v* Q = (const i4v*)csr;
    h2v a0 = {(_Float16)0.f, (_Float16)0.f};
    h2v a1 = a0, a2 = a0, a3 = a0;
    int q = q0;
    for (; q + 2 <= q1; q += 2) {
        i4v c0 = Q[q], c1 = Q[q + 1];
        a0 += *(const h2v*)(T + ((unsigned)c0.x * 32u + fo));
        a1 += *(const h2v*)(T + ((unsigned)c0.y * 32u + fo));
        a2 += *(const h2v*)(T + ((unsigned)c0.z * 32u + fo));
        a3 += *(const h2v*)(T + ((unsigned)c0.w * 32u + fo));
        a0 += *(const h2v*)(T + ((unsigned)c1.x * 32u + fo));
        a1 += *(const h2v*)(T + ((unsigned)c1.y * 32u + fo));
        a2 += *(const h2v*)(T + ((unsigned)c1.z * 32u + fo));
        a3 += *(const h2v*)(T + ((unsigned)c1.w * 32u + fo));
    }
    if (q < q1) {
        i4v c0 = Q[q];
        a0 += *(const h2v*)(T + ((unsigned)c0.x * 32u + fo));
        a1 += *(const h2v*)(T + ((unsigned)c0.y * 32u + fo));
        a2 += *(const h2v*)(T + ((unsigned)c0.z * 32u + fo));
        a3 += *(const h2v*)(T + ((unsigned)c0.w * 32u + fo));
    }
    h2v self = *(const h2v*)(T + ((unsigned)n * 32u + fo));
    float dv = dinv[n];
    int fb = fp * 2;
    float sx = ((float)a0.x + (float)a1.x) + ((float)a2.x + (float)a3.x) + (float)self.x;
    float sy = ((float)a0.y + (float)a1.y) + ((float)a2.y + (float)a3.y) + (float)self.y;
    float ox = dv * sx + b2[fb];
    float oy = dv * sy + b2[fb + 1];
    *(float2*)(out + (size_t)n * F_OUT + fb) = make_float2(ox, oy);
}

extern "C" void kernel_launch(void* const* d_in, const int* in_sizes, int n_in,
                              void* d_out, int out_size, void* d_ws, size_t ws_size,
                              hipStream_t stream) {
    const float* x  = (const float*)d_in[0];
    const void*  ei = d_in[1];
    const float* W1 = (const float*)d_in[2];
    const float* b1 = (const float*)d_in[3];
    const float* W2 = (const float*)d_in[4];
    const float* b2 = (const float*)d_in[5];
    float* out = (float*)d_out;

    char* ws = (char*)d_ws;
    int*      rowend   = (int*)(ws + OFF_RE);
    int*      rowstart = (int*)(ws + OFF_RS);
    float*    dinv     = (float*)(ws + OFF_DINV);
    int*      gcnt     = (int*)(ws + OFF_GCNT);
    int*      csr      = (int*)(ws + OFF_CSR);
    __half*   hs1      = (__half*)(ws + OFF_HS1);
    float*    out1     = (float*)(ws + OFF_OUT1);
    __half*   hs2      = (__half*)(ws + OFF_HS2);
    unsigned* pairs    = (unsigned*)(ws + OFF_PAIRS);

    hipMemsetAsync(gcnt, 0, NBUCK * sizeof(int), stream);

    // CSR build: 2 kernels (partition, then fused count/scan/place per bucket)
    k_partition<<<NBLK_P, 256, 0, stream>>>(ei, gcnt, pairs);
    k_build    <<<NBUCK, 512, 0, stream>>>(pairs, gcnt, rowstart, rowend, dinv, csr);

    // GCN layers
    k_gemm1<<<G1_BLOCKS, 256, 0, stream>>>(x, W1, dinv, hs1);
    k_agg1 <<<12500, 256, 0, stream>>>(hs1, csr, rowstart, rowend, dinv, b1, out1);
    k_gemm2<<<(N_TAB * 4 + 255) / 256, 256, 0, stream>>>(out1, W2, dinv, hs2);
    k_agg2 <<<3125, 256, 0, stream>>>(hs2, csr, rowstart, rowend, dinv, b2, out);
}

// Round 11
// 326.363 us; speedup vs baseline: 1.2905x; 1.0487x over previous
//
#include <hip/hip_runtime.h>
#include <hip/hip_fp16.h>
#include <stdint.h>

#define N_NODES   100000
#define N_TAB     (N_NODES + 1)   // +1 sentinel zero-row for CSR padding
#define N_EDGES   3200000
#define F_IN      128
#define F_HID     64
#define F_OUT     16

typedef _Float16 h2v __attribute__((ext_vector_type(2)));
typedef int   i4v __attribute__((ext_vector_type(4)));

// bucket partition params
#define BSHIFT    8
#define NBUCK     391                  // ceil(100000 / 256)
#define NBLK_P    512                  // partition blocks
#define CHUNK_E   (N_EDGES / NBLK_P)   // 6250 edges per block
#define PSTRIDE   9472                 // bucket region capacity (mean padded 8576 + ~10 sigma), mult of 4

// gemm1 tiling
#define G1_TM     128
#define G1_BLOCKS ((N_TAB + G1_TM - 1) / G1_TM)   // 782
#define XS_LD     132

// ---- workspace layout (bytes), 16B-aligned ----
#define OFF_RE       0                 // int[N]    rowend (padded) per node
#define OFF_RS       400000            // int[N]    rowstart per node (bucket-local CSR)
#define OFF_DINV     800000            // float[N+1]
#define OFF_GCNT     1200016           // int[NBUCK]
#define OFF_FLAG     1201600           // int       1 => edge_index is int64
#define OFF_CSR      1201616           // int[NBUCK*PSTRIDE] = 14,814,208 B
#define OFF_HS1      16015824          // half[2][N_TAB][32]  (32-feat chunk-major)
#define OFF_OUT1     28815952          // float[N*64] = 25.6 MB
#define OFF_HS2      54415952          // half[N_TAB*16]
#define OFF_PAIRS    OFF_OUT1          // uint[NBUCK*PSTRIDE] = 14.8 MB, aliases out1
// total ~57.6 MB

__device__ __forceinline__ int edge_src(const void* ei, int is64, int e) {
    return is64 ? (int)((const long long*)ei)[e] : ((const int*)ei)[e];
}
__device__ __forceinline__ int edge_dst(const void* ei, int is64, int e) {
    return is64 ? (int)((const long long*)ei)[N_EDGES + e]
                : ((const int*)ei)[N_EDGES + e];
}

// ---- init: zero gcnt + one-time dtype detect (replaces memset + per-block chains)
__global__ void k_init(const void* __restrict__ ei, int* __restrict__ gcnt,
                       int* __restrict__ flag) {
    int t = threadIdx.x;
    for (int i = t; i < NBUCK; i += 512) gcnt[i] = 0;
    if (t == 0) {
        // int64 data viewed as u32 pairs: [lo<100000, hi==0] x 64. For int32
        // data the hi words are random node ids: P(all zero) ~ 0.
        const unsigned* u = (const unsigned*)ei;
        int ok = 1;
        for (int i = 0; i < 64; ++i) {
            unsigned lo = u[2 * i], hi = u[2 * i + 1];
            if (hi != 0u || lo >= 100000u) { ok = 0; break; }
        }
        *flag = ok;
    }
}

// ---- pass 1: partition edges into fixed-capacity bucket regions ------------
__global__ __launch_bounds__(256) void k_partition(const void* __restrict__ ei,
                                                   const int* __restrict__ flag,
                                                   int* __restrict__ gcnt,
                                                   unsigned* __restrict__ pairs) {
    __shared__ int h[NBUCK];
    __shared__ int cur[NBUCK];
    int t = threadIdx.x;
    for (int i = t; i < NBUCK; i += 256) h[i] = 0;
    __syncthreads();
    int is64 = *flag;
    int base = blockIdx.x * CHUNK_E;
    for (int i = t; i < CHUNK_E; i += 256)
        atomicAdd(&h[edge_dst(ei, is64, base + i) >> BSHIFT], 1);
    __syncthreads();
    for (int i = t; i < NBUCK; i += 256) {
        int c = h[i];
        cur[i] = c ? atomicAdd(&gcnt[i], c) : 0;
    }
    __syncthreads();
    for (int i = t; i < CHUNK_E; i += 256) {
        int e = base + i;
        int s = edge_src(ei, is64, e);
        int d = edge_dst(ei, is64, e);
        int b = d >> BSHIFT;
        int p = atomicAdd(&cur[b], 1);
        if (p < PSTRIDE)   // statistically impossible to overflow; guard anyway
            pairs[b * PSTRIDE + p] = ((unsigned)s << 8) | (unsigned)(d & 255);
    }
}

// ---- pass 2: per-bucket count + scan + dinv + CSR place (single kernel) ----
// Bucket-local CSR: node rows live inside bucket b's [b*PSTRIDE, ...) region,
// quad-padded with sentinel N_NODES. rowstart/rowend are absolute indices.
__global__ __launch_bounds__(512) void k_build(const unsigned* __restrict__ pairs,
                                               const int* __restrict__ gcnt,
                                               int* __restrict__ rowstart,
                                               int* __restrict__ rowend,
                                               float* __restrict__ dinv,
                                               int* __restrict__ csr) {
    __shared__ int cntS[256], scanS[256], posS[256];
    int b = blockIdx.x, t = threadIdx.x;
    if (t < 256) cntS[t] = 0;
    __syncthreads();
    int tot = gcnt[b]; if (tot > PSTRIDE) tot = PSTRIDE;
    int base = b * PSTRIDE;
    for (int i = t; i < tot; i += 512)
        atomicAdd(&cntS[pairs[base + i] & 255u], 1);
    __syncthreads();
    int padded = 0;
    if (t < 256) { padded = (cntS[t] + 3) & ~3; scanS[t] = padded; }
    __syncthreads();
    for (int off = 1; off < 256; off <<= 1) {
        int add = 0;
        if (t < 256 && t >= off) add = scanS[t - off];
        __syncthreads();
        if (t < 256) scanS[t] += add;
        __syncthreads();
    }
    if (t < 256) {
        int rs = base + scanS[t] - padded;   // exclusive scan, quad-aligned
        posS[t] = rs;
        int d = (b << BSHIFT) + t;
        if (d < N_NODES) {
            rowstart[d] = rs;
            rowend[d]   = rs + padded;
            dinv[d] = rsqrtf((float)cntS[t] + 1.0f);
            for (int j = cntS[t]; j < padded; ++j) csr[rs + j] = N_NODES; // pad
        } else if (d == N_NODES) {
            dinv[d] = 0.f;   // sentinel
        }
    }
    __syncthreads();
    for (int i = t; i < tot; i += 512) {
        unsigned pr = pairs[base + i];
        int p = atomicAdd(&posS[pr & 255u], 1);
        csr[p] = (int)(pr >> 8);
    }
}

// ---- GEMM1 (LDS-tiled): hs1[chunk32][node][32] = (x@W1)*dinv ---------------
__global__ __launch_bounds__(256) void k_gemm1(const float* __restrict__ x,
                                               const float* __restrict__ W1,
                                               const float* __restrict__ dinv,
                                               __half* __restrict__ hs1) {
    __shared__ float xsT[64 * XS_LD];
    __shared__ float ws[64 * 64];
    int t = threadIdx.x;
    int nblock = blockIdx.x * G1_TM;
    int ng = t >> 4, og = t & 15;
    int n0 = ng * 8;
    float acc[8][4] = {};

    int snode = nblock + (t >> 1);
    int koff = (t & 1) * 32;
    int nl = t >> 1;

    for (int chunk = 0; chunk < 2; ++chunk) {
        int kbase = chunk * 64;
        {
            float4 v[8];
            if (snode < N_NODES) {
                const float4* src = (const float4*)(x + (size_t)snode * F_IN + kbase + koff);
#pragma unroll
                for (int c = 0; c < 8; ++c) v[c] = src[c];
            } else {
#pragma unroll
                for (int c = 0; c < 8; ++c) v[c] = make_float4(0.f, 0.f, 0.f, 0.f);
            }
#pragma unroll
            for (int c = 0; c < 8; ++c) {
                int k = koff + c * 4;
                xsT[(k + 0) * XS_LD + nl] = v[c].x;
                xsT[(k + 1) * XS_LD + nl] = v[c].y;
                xsT[(k + 2) * XS_LD + nl] = v[c].z;
                xsT[(k + 3) * XS_LD + nl] = v[c].w;
            }
        }
        {
            const float4* wsrc = (const float4*)(W1 + kbase * F_HID);
            float4* wdst = (float4*)ws;
#pragma unroll
            for (int c = 0; c < 4; ++c) wdst[c * 256 + t] = wsrc[c * 256 + t];
        }
        __syncthreads();

#pragma unroll 4
        for (int k = 0; k < 64; ++k) {
            const float4* xr = (const float4*)(xsT + k * XS_LD + n0);
            float4 a0 = xr[0], a1 = xr[1];
            float4 bv = *(const float4*)(ws + k * 64 + og * 4);
            float a[8] = {a0.x, a0.y, a0.z, a0.w, a1.x, a1.y, a1.z, a1.w};
            float bb[4] = {bv.x, bv.y, bv.z, bv.w};
#pragma unroll
            for (int i = 0; i < 8; ++i)
#pragma unroll
                for (int j = 0; j < 4; ++j)
                    acc[i][j] += a[i] * bb[j];
        }
        __syncthreads();
    }

    // epilogue: 32-feat chunk-major layout hs1[(og>>3)*N_TAB + node][32] + (og&7)*4
#pragma unroll
    for (int i = 0; i < 8; ++i) {
        int node = nblock + n0 + i;
        if (node < N_TAB) {
            float dv = dinv[node];   // dinv[N_NODES]=0 -> sentinel row zeros
            union { __half2 h[2]; float2 f; } u;
            u.h[0] = __floats2half2_rn(acc[i][0] * dv, acc[i][1] * dv);
            u.h[1] = __floats2half2_rn(acc[i][2] * dv, acc[i][3] * dv);
            *(float2*)(hs1 + ((size_t)(og >> 3) * N_TAB + node) * 32 + (og & 7) * 4) = u.f;
        }
    }
}

// ---- aggregate layer 1: 2 XCD-pinned passes, 64B rows ----------------------
// chunk = bid & 1: chunk 0 runs on even XCDs, chunk 1 on odd (round-robin
// bid%8 -> XCD). One full-line 64B access per edge per pass: total L2 gather
// transactions halve vs the 4x16-feat scheme. Table 6.4MB: ~60% L2-resident,
// misses served from L3 (whole 12.8MB resident there — no extra HBM).
// wave = 4 nodes (slot) x 16 featpairs; unroll-2, 4 fp16x2 accumulators.
__global__ __launch_bounds__(256) void k_agg1(const __half* __restrict__ hs1,
                                              const int* __restrict__ csr,
                                              const int* __restrict__ rowstart,
                                              const int* __restrict__ rowend,
                                              const float* __restrict__ dinv,
                                              const float* __restrict__ b1,
                                              float* __restrict__ out1) {
    int bid = blockIdx.x;            // grid = 12500
    int chunk = bid & 1;
    int nb = bid >> 1;               // 0..6249
    int w = threadIdx.x >> 6, lane = threadIdx.x & 63;
    int slot = lane >> 4, fp = lane & 15;
    int n = nb * 16 + w * 4 + slot;  // 6250*16 = 100000 exact
    const char* T = (const char*)(hs1 + (size_t)chunk * ((size_t)N_TAB * 32));
    unsigned fo = fp * 4u;
    int q0 = rowstart[n] >> 2, q1 = rowend[n] >> 2;
    const i4v* Q = (const i4v*)csr;
    h2v a0 = {(_Float16)0.f, (_Float16)0.f};
    h2v a1 = a0, a2 = a0, a3 = a0;
    int q = q0;
    for (; q + 2 <= q1; q += 2) {
        i4v c0 = Q[q], c1 = Q[q + 1];
        a0 += *(const h2v*)(T + ((unsigned)c0.x * 64u + fo));
        a1 += *(const h2v*)(T + ((unsigned)c0.y * 64u + fo));
        a2 += *(const h2v*)(T + ((unsigned)c0.z * 64u + fo));
        a3 += *(const h2v*)(T + ((unsigned)c0.w * 64u + fo));
        a0 += *(const h2v*)(T + ((unsigned)c1.x * 64u + fo));
        a1 += *(const h2v*)(T + ((unsigned)c1.y * 64u + fo));
        a2 += *(const h2v*)(T + ((unsigned)c1.z * 64u + fo));
        a3 += *(const h2v*)(T + ((unsigned)c1.w * 64u + fo));
    }
    if (q < q1) {
        i4v c0 = Q[q];
        a0 += *(const h2v*)(T + ((unsigned)c0.x * 64u + fo));
        a1 += *(const h2v*)(T + ((unsigned)c0.y * 64u + fo));
        a2 += *(const h2v*)(T + ((unsigned)c0.z * 64u + fo));
        a3 += *(const h2v*)(T + ((unsigned)c0.w * 64u + fo));
    }
    h2v self = *(const h2v*)(T + ((unsigned)n * 64u + fo));
    float dv = dinv[n];
    int fb = chunk * 32 + fp * 2;
    float sx = ((float)a0.x + (float)a1.x) + ((float)a2.x + (float)a3.x) + (float)self.x;
    float sy = ((float)a0.y + (float)a1.y) + ((float)a2.y + (float)a3.y) + (float)self.y;
    float ox = fmaxf(dv * sx + b1[fb], 0.f);
    float oy = fmaxf(dv * sy + b1[fb + 1], 0.f);
    *(float2*)(out1 + (size_t)n * F_HID + fb) = make_float2(ox, oy);
}

// ---- GEMM2: hs2 = (out1 @ W2) * dinv, fp16, W2 in LDS ----------------------
__global__ __launch_bounds__(256) void k_gemm2(const float* __restrict__ h,
                                               const float* __restrict__ W2,
                                               const float* __restrict__ dinv,
                                               __half* __restrict__ hs2) {
    __shared__ float ws[F_HID * F_OUT];
    int t = threadIdx.x;
    ((float4*)ws)[t] = ((const float4*)W2)[t];
    __syncthreads();
    int tid = blockIdx.x * 256 + t;
    int n = tid >> 2;
    if (n > N_NODES) return;
    int cq = (tid & 3) << 2;
    if (n == N_NODES) {   // sentinel zero row
        *(float2*)(hs2 + (size_t)n * F_OUT + cq) = make_float2(0.f, 0.f);
        return;
    }
    const float4* h4 = (const float4*)(h + (size_t)n * F_HID);
    float4 acc = make_float4(0.f, 0.f, 0.f, 0.f);
#pragma unroll 4
    for (int k4 = 0; k4 < 16; ++k4) {
        float4 hv = h4[k4];
        float4 w0 = *(const float4*)(ws + (k4 * 4 + 0) * F_OUT + cq);
        float4 w1 = *(const float4*)(ws + (k4 * 4 + 1) * F_OUT + cq);
        float4 w2 = *(const float4*)(ws + (k4 * 4 + 2) * F_OUT + cq);
        float4 w3 = *(const float4*)(ws + (k4 * 4 + 3) * F_OUT + cq);
        acc.x += hv.x * w0.x + hv.y * w1.x + hv.z * w2.x + hv.w * w3.x;
        acc.y += hv.x * w0.y + hv.y * w1.y + hv.z * w2.y + hv.w * w3.y;
        acc.z += hv.x * w0.z + hv.y * w1.z + hv.z * w2.z + hv.w * w3.z;
        acc.w += hv.x * w0.w + hv.y * w1.w + hv.z * w2.w + hv.w * w3.w;
    }
    float dv = dinv[n];
    union { __half2 h2[2]; float2 f; } u;
    u.h2[0] = __floats2half2_rn(acc.x * dv, acc.y * dv);
    u.h2[1] = __floats2half2_rn(acc.z * dv, acc.w * dv);
    *(float2*)(hs2 + (size_t)n * F_OUT + cq) = u.f;
}

// ---- aggregate layer 2: single pass (3.2MB table), unroll-by-2 -------------
__global__ __launch_bounds__(256) void k_agg2(const __half* __restrict__ hs2,
                                              const int* __restrict__ csr,
                                              const int* __restrict__ rowstart,
                                              const int* __restrict__ rowend,
                                              const float* __restrict__ dinv,
                                              const float* __restrict__ b2,
                                              float* __restrict__ out) {
    int w = threadIdx.x >> 6, lane = threadIdx.x & 63;
    int slot = lane >> 3, fp = lane & 7;
    int n = blockIdx.x * 32 + w * 8 + slot;   // grid = 3125
    const char* T = (const char*)hs2;
    unsigned fo = fp * 4u;
    int q0 = rowstart[n] >> 2, q1 = rowend[n] >> 2;
    const i4v* Q = (const i4v*)csr;
    h2v a0 = {(_Float16)0.f, (_Float16)0.f};
    h2v a1 = a0, a2 = a0, a3 = a0;
    int q = q0;
    for (; q + 2 <= q1; q += 2) {
        i4v c0 = Q[q], c1 = Q[q + 1];
        a0 += *(const h2v*)(T + ((unsigned)c0.x * 32u + fo));
        a1 += *(const h2v*)(T + ((unsigned)c0.y * 32u + fo));
        a2 += *(const h2v*)(T + ((unsigned)c0.z * 32u + fo));
        a3 += *(const h2v*)(T + ((unsigned)c0.w * 32u + fo));
        a0 += *(const h2v*)(T + ((unsigned)c1.x * 32u + fo));
        a1 += *(const h2v*)(T + ((unsigned)c1.y * 32u + fo));
        a2 += *(const h2v*)(T + ((unsigned)c1.z * 32u + fo));
        a3 += *(const h2v*)(T + ((unsigned)c1.w * 32u + fo));
    }
    if (q < q1) {
        i4v c0 = Q[q];
        a0 += *(const h2v*)(T + ((unsigned)c0.x * 32u + fo));
        a1 += *(const h2v*)(T + ((unsigned)c0.y * 32u + fo));
        a2 += *(const h2v*)(T + ((unsigned)c0.z * 32u + fo));
        a3 += *(const h2v*)(T + ((unsigned)c0.w * 32u + fo));
    }
    h2v self = *(const h2v*)(T + ((unsigned)n * 32u + fo));
    float dv = dinv[n];
    int fb = fp * 2;
    float sx = ((float)a0.x + (float)a1.x) + ((float)a2.x + (float)a3.x) + (float)self.x;
    float sy = ((float)a0.y + (float)a1.y) + ((float)a2.y + (float)a3.y) + (float)self.y;
    float ox = dv * sx + b2[fb];
    float oy = dv * sy + b2[fb + 1];
    *(float2*)(out + (size_t)n * F_OUT + fb) = make_float2(ox, oy);
}

extern "C" void kernel_launch(void* const* d_in, const int* in_sizes, int n_in,
                              void* d_out, int out_size, void* d_ws, size_t ws_size,
                              hipStream_t stream) {
    const float* x  = (const float*)d_in[0];
    const void*  ei = d_in[1];
    const float* W1 = (const float*)d_in[2];
    const float* b1 = (const float*)d_in[3];
    const float* W2 = (const float*)d_in[4];
    const float* b2 = (const float*)d_in[5];
    float* out = (float*)d_out;

    char* ws = (char*)d_ws;
    int*      rowend   = (int*)(ws + OFF_RE);
    int*      rowstart = (int*)(ws + OFF_RS);
    float*    dinv     = (float*)(ws + OFF_DINV);
    int*      gcnt     = (int*)(ws + OFF_GCNT);
    int*      flag     = (int*)(ws + OFF_FLAG);
    int*      csr      = (int*)(ws + OFF_CSR);
    __half*   hs1      = (__half*)(ws + OFF_HS1);
    float*    out1     = (float*)(ws + OFF_OUT1);
    __half*   hs2      = (__half*)(ws + OFF_HS2);
    unsigned* pairs    = (unsigned*)(ws + OFF_PAIRS);

    // CSR build: init + partition + fused count/scan/place per bucket
    k_init     <<<1, 512, 0, stream>>>(ei, gcnt, flag);
    k_partition<<<NBLK_P, 256, 0, stream>>>(ei, flag, gcnt, pairs);
    k_build    <<<NBUCK, 512, 0, stream>>>(pairs, gcnt, rowstart, rowend, dinv, csr);

    // GCN layers
    k_gemm1<<<G1_BLOCKS, 256, 0, stream>>>(x, W1, dinv, hs1);
    k_agg1 <<<12500, 256, 0, stream>>>(hs1, csr, rowstart, rowend, dinv, b1, out1);
    k_gemm2<<<(N_TAB * 4 + 255) / 256, 256, 0, stream>>>(out1, W2, dinv, hs2);
    k_agg2 <<<3125, 256, 0, stream>>>(hs2, csr, rowstart, rowend, dinv, b2, out);
}